// Round 7
// baseline (2490.918 us; speedup 1.0000x reference)
//
#include <hip/hip_runtime.h>

#define HW 1024
#define NIMG 32
#define IMGPX ((size_t)HW * HW)
#define NELEM (NIMG * IMGPX)

typedef float f2 __attribute__((ext_vector_type(2)));

// region 128x128 per block, ring 6 -> out 116x116
#define RING 6
#define TOUT 116
#define NB 9
#define LSTR 136   // words per LDS row slot; col c(0..127)->word c; col -1 ->130; col 128 ->131
#define SLOTS 66   // boundary rows: -1, {0,3 mod 4}, 128

// ---- float <-> order-preserving unsigned (for atomic min/max) ----
__device__ __forceinline__ unsigned f2su(float f) {
    unsigned u = __float_as_uint(f);
    return (u & 0x80000000u) ? ~u : (u | 0x80000000u);
}
__device__ __forceinline__ float s2f(unsigned u) {
    return __uint_as_float((u & 0x80000000u) ? (u & 0x7fffffffu) : ~u);
}

__global__ void mm_init(unsigned* mm) {
    mm[0] = 0xFFFFFFFFu;
    mm[1] = 0u;
}

__global__ __launch_bounds__(256) void mm_reduce(const float4* __restrict__ x,
                                                 unsigned* mm, int n4) {
    const int tid = threadIdx.x;
    int gid = blockIdx.x * blockDim.x + tid;
    const int stride = gridDim.x * blockDim.x;
    float vmin = 3.4e38f, vmax = -3.4e38f;
    for (int i = gid; i < n4; i += stride) {
        float4 v = x[i];
        vmin = fminf(vmin, fminf(fminf(v.x, v.y), fminf(v.z, v.w)));
        vmax = fmaxf(vmax, fmaxf(fmaxf(v.x, v.y), fmaxf(v.z, v.w)));
    }
    __shared__ float smin[256];
    __shared__ float smax[256];
    smin[tid] = vmin; smax[tid] = vmax;
    __syncthreads();
    for (int s = 128; s > 0; s >>= 1) {
        if (tid < s) {
            smin[tid] = fminf(smin[tid], smin[tid + s]);
            smax[tid] = fmaxf(smax[tid], smax[tid + s]);
        }
        __syncthreads();
    }
    if (tid == 0) {
        atomicMin(&mm[0], f2su(smin[0]));
        atomicMax(&mm[1], f2su(smax[0]));
    }
}

struct RowW { f2 P[4]; float L, R; };

// slot index for boundary row r in {-1, 0,3,4,7,...,124,127, 128}
__device__ __forceinline__ int bslot(int r) {
    return (r == -1) ? 0 : ((r == 128) ? 65 : ((r >> 2) * 2 + 1 + (((r & 3) == 3) ? 1 : 0)));
}

// 512 threads: tx 0..15 owns 8 cols (4 f2 pairs), tyg 0..31 owns 4 rows.
// State in registers; LDS = 66 boundary-row slots (36 KB) reused for xn half-tiles.
template <int FIRST, int LAST>
__global__ __launch_bounds__(512, 6) void fused_k(
    const float* __restrict__ x, const float* __restrict__ sin_,
    float* __restrict__ sout, const unsigned* __restrict__ mm,
    const float* __restrict__ wAp, const float* __restrict__ wBp,
    const float* __restrict__ biasp) {
#pragma clang fp contract(off)
    __shared__ float sb[SLOTS * LSTR];
    const int tid = threadIdx.x;
    const int tx = tid & 15;
    const int tyg = tid >> 4;
    const int lane = tid & 63;
    const int laneL = (lane + 63) & 63;
    const int laneR = (lane + 1) & 63;
    const int r0 = tyg << 2;
    const int c0 = tx << 3;
    const int ox = (int)blockIdx.x * TOUT - RING;
    const int oy = (int)blockIdx.y * TOUT - RING;
    const size_t img = (size_t)blockIdx.z * IMGPX;
    const bool edgeX = (blockIdx.x == 0) | (blockIdx.x == NB - 1);

    const float xmin = s2f(mm[0]);
    const float xmax = s2f(mm[1]);
    const float scale = 2.0f / (xmax - xmin);
    const float b = biasp[0];

    // aligned b128x2 + shfl row loader from an LDS slot
    auto ldSlot = [&](int slot) -> RowW {
        RowW o;
        const int base = slot * LSTR;
        const float4 q0 = *reinterpret_cast<const float4*>(&sb[base + c0]);
        const float4 q1 = *reinterpret_cast<const float4*>(&sb[base + c0 + 4]);
        o.P[0] = f2{q0.x, q0.y}; o.P[1] = f2{q0.z, q0.w};
        o.P[2] = f2{q1.x, q1.y}; o.P[3] = f2{q1.z, q1.w};
        const float fromL = __shfl(q1.w, laneL);
        const float fromR = __shfl(q0.x, laneR);
        o.L = (tx == 0) ? sb[base + 130] : fromL;
        o.R = (tx == 15) ? sb[base + 131] : fromR;
        return o;
    };

    float cf[9];
    // 9-term sequential row-major conv for pixel pair p (exact numpy order per element)
    auto conv9 = [&](const RowW& A, const RowW& B, const RowW& C, int p) -> f2 {
#pragma clang fp contract(off)
        f2 acc = f2{0.0f, 0.0f};
        f2 tl, tr;
        tl = f2{(p == 0) ? A.L : A.P[p - 1].y, A.P[p].x};
        tr = f2{A.P[p].y, (p == 3) ? A.R : A.P[p + 1].x};
        acc = acc + f2{cf[0], cf[0]} * tl;
        acc = acc + f2{cf[1], cf[1]} * A.P[p];
        acc = acc + f2{cf[2], cf[2]} * tr;
        tl = f2{(p == 0) ? B.L : B.P[p - 1].y, B.P[p].x};
        tr = f2{B.P[p].y, (p == 3) ? B.R : B.P[p + 1].x};
        acc = acc + f2{cf[3], cf[3]} * tl;
        acc = acc + f2{cf[4], cf[4]} * B.P[p];
        acc = acc + f2{cf[5], cf[5]} * tr;
        tl = f2{(p == 0) ? C.L : C.P[p - 1].y, C.P[p].x};
        tr = f2{C.P[p].y, (p == 3) ? C.R : C.P[p + 1].x};
        acc = acc + f2{cf[6], cf[6]} * tl;
        acc = acc + f2{cf[7], cf[7]} * C.P[p];
        acc = acc + f2{cf[8], cf[8]} * tr;
        return acc;
    };

    // stage 66 consecutive xn rows (starting at region row row0s) into slots 0..65
    auto stageXn = [&](int row0s) {
        for (int k = tid; k < SLOTS * 130; k += 512) {
            const int si = k / 130;
            const int ci = k - si * 130;
            const int cc = ci - 1;
            const int w = (cc == -1) ? 130 : ((cc == 128) ? 131 : cc);
            const int gr = oy + row0s + si;
            const int gc = ox + cc;
            float v = 0.0f;
            if (gr >= 0 && gr < HW && gc >= 0 && gc < HW)
                v = (x[img + (size_t)gr * HW + gc] - xmin) * scale - 1.0f;
            sb[si * LSTR + w] = v;
        }
    };

    // ---- phase 1+2: BU = conv(xn, B) via two xn half-tiles through LDS ----
#pragma unroll
    for (int i = 0; i < 9; ++i) cf[i] = wBp[i];
    f2 bu[4][4];
    {
        stageXn(-1);          // rows -1..64 -> slot = r + 1
        __syncthreads();
        if (tyg < 16) {       // rows r0-1..r0+4 in [-1,64]; window row r0-1+i -> slot r0+i
            RowW ra = ldSlot(r0), rb = ldSlot(r0 + 1);
#pragma unroll
            for (int i = 0; i < 4; ++i) {
                RowW rc = ldSlot(r0 + 2 + i);
#pragma unroll
                for (int p = 0; p < 4; ++p) bu[i][p] = conv9(ra, rb, rc, p);
                ra = rb; rb = rc;
            }
        }
        __syncthreads();
        stageXn(63);          // rows 63..128 -> slot = r - 63
        __syncthreads();
        if (tyg >= 16) {      // window row r0-1+i -> slot r0-64+i
            const int s0 = r0 - 64;
            RowW ra = ldSlot(s0), rb = ldSlot(s0 + 1);
#pragma unroll
            for (int i = 0; i < 4; ++i) {
                RowW rc = ldSlot(s0 + 2 + i);
#pragma unroll
                for (int p = 0; p < 4; ++p) bu[i][p] = conv9(ra, rb, rc, p);
                ra = rb; rb = rc;
            }
        }
        __syncthreads();
    }

    // ---- phase 3: stage s into registers + boundary slots ----
    f2 res[4][4];
    float hL[4], hR[4];
    // slot halo fill: rows -1 & 128 full width (260 items) + cols -1/128 of rows 0,3 mod 4 (128 items)
    for (int k = tid; k < 388; k += 512) {
        int rr, cc;
        if (k < 260) { rr = (k < 130) ? -1 : 128; cc = (k % 130) - 1; }
        else {
            const int kk = k - 260;
            const int s = (kk >> 1) + 1;  // 1..64
            rr = (s & 1) ? (((s - 1) >> 1) << 2) : ((((s - 2) >> 1) << 2) + 3);
            cc = (kk & 1) ? 128 : -1;
        }
        const int w = (cc == -1) ? 130 : ((cc == 128) ? 131 : cc);
        float v = 0.0f;
        if (!FIRST) {
            const int gr = oy + rr, gc = ox + cc;
            if (gr >= 0 && gr < HW && gc >= 0 && gc < HW)
                v = sin_[img + (size_t)gr * HW + gc];
        }
        sb[bslot(rr) * LSTR + w] = v;
    }
    if (FIRST) {
#pragma unroll
        for (int i = 0; i < 4; ++i) {
            hL[i] = 0.0f; hR[i] = 0.0f;
#pragma unroll
            for (int p = 0; p < 4; ++p) res[i][p] = f2{0.0f, 0.0f};
        }
    } else {
#pragma unroll
        for (int i = 0; i < 4; ++i) {
            const int gr = oy + r0 + i;
            const bool rin = (gr >= 0) & (gr < HW);
            if (!edgeX && rin) {
                const float2* src = reinterpret_cast<const float2*>(&sin_[img + (size_t)gr * HW + ox + c0]);
#pragma unroll
                for (int p = 0; p < 4; ++p) { const float2 t = src[p]; res[i][p] = f2{t.x, t.y}; }
            } else {
#pragma unroll
                for (int cl = 0; cl < 8; ++cl) {
                    const int gc = ox + c0 + cl;
                    float v = 0.0f;
                    if (rin && gc >= 0 && gc < HW) v = sin_[img + (size_t)gr * HW + gc];
                    res[i][cl >> 1][cl & 1] = v;
                }
            }
            const int gcl = ox - 1, gcr = ox + 128;
            hL[i] = (rin && gcl >= 0) ? sin_[img + (size_t)gr * HW + gcl] : 0.0f;
            hR[i] = (rin && gcr < HW) ? sin_[img + (size_t)gr * HW + gcr] : 0.0f;
        }
    }

    auto wrRow = [&](int i, int slot) {
        const int base = slot * LSTR + c0;
        *reinterpret_cast<float4*>(&sb[base]) =
            make_float4(res[i][0].x, res[i][0].y, res[i][1].x, res[i][1].y);
        *reinterpret_cast<float4*>(&sb[base + 4]) =
            make_float4(res[i][2].x, res[i][2].y, res[i][3].x, res[i][3].y);
    };
    wrRow(0, 2 * tyg + 1); wrRow(3, 2 * tyg + 2);
    __syncthreads();

    // ---- phase 4: 7 fused steps, state in registers ----
#pragma unroll
    for (int i = 0; i < 9; ++i) cf[i] = wAp[i];
    const f2 b2 = f2{b, b};
    f2 mR2[4], mC2[4];
#pragma unroll
    for (int i = 0; i < 4; ++i) {
        const int g = oy + r0 + i;
        const float m = (g >= 0 && g < HW) ? 1.0f : 0.0f;
        mR2[i] = f2{m, m};
    }
#pragma unroll
    for (int p = 0; p < 4; ++p) {
        const int g0 = ox + c0 + 2 * p, g1 = g0 + 1;
        mC2[p] = f2{(g0 >= 0 && g0 < HW) ? 1.0f : 0.0f,
                    (g1 >= 0 && g1 < HW) ? 1.0f : 0.0f};
    }

    const int slotM1 = (tyg == 0) ? 0 : 2 * tyg;
    const int slotP4 = (tyg == 31) ? 65 : 2 * tyg + 3;

#pragma unroll 1
    for (int t = 0; t < 7; ++t) {
        const RowW m1 = ldSlot(slotM1);
        const RowW p4 = ldSlot(slotP4);
        __syncthreads();  // all reads of old boundary rows complete

        RowW o[4];
#pragma unroll
        for (int i = 0; i < 4; ++i) {
            o[i].P[0] = res[i][0]; o[i].P[1] = res[i][1];
            o[i].P[2] = res[i][2]; o[i].P[3] = res[i][3];
            const float fromL = __shfl(res[i][3].y, laneL);
            const float fromR = __shfl(res[i][0].x, laneR);
            o[i].L = (tx == 0) ? hL[i] : fromL;
            o[i].R = (tx == 15) ? hR[i] : fromR;
        }
        f2 nw[4][4];
#pragma unroll
        for (int i = 0; i < 4; ++i) {
            const RowW& A = (i == 0) ? m1 : o[i - 1];
            const RowW& B = o[i];
            const RowW& C = (i == 3) ? p4 : o[i + 1];
#pragma unroll
            for (int p = 0; p < 4; ++p) {
                f2 v = conv9(A, B, C, p);
                v = (v + b2) + bu[i][p];
                v = __builtin_elementwise_max(v, f2{-1.0f, -1.0f});
                v = __builtin_elementwise_min(v, f2{1.0f, 1.0f});
                v = v * mR2[i];
                v = v * mC2[p];
                nw[i][p] = v;
            }
        }
#pragma unroll
        for (int i = 0; i < 4; ++i)
#pragma unroll
            for (int p = 0; p < 4; ++p) res[i][p] = nw[i][p];
        wrRow(0, 2 * tyg + 1); wrRow(3, 2 * tyg + 2);
        __syncthreads();  // new boundary rows visible
    }

    // ---- phase 5: store inner 116x116 tile ----
#pragma unroll
    for (int i = 0; i < 4; ++i) {
        const int r = r0 + i;
        if (r < RING || r >= RING + TOUT) continue;
        const int gr = oy + r;
        if (gr >= HW) continue;
        if (!edgeX && tx >= 1 && tx <= 14) {
            float2* dst = reinterpret_cast<float2*>(&sout[img + (size_t)gr * HW + ox + c0]);
#pragma unroll
            for (int p = 0; p < 4; ++p) {
                f2 v = res[i][p];
                if (LAST) v = (v + f2{1.0f, 1.0f}) * f2{0.5f, 0.5f};
                dst[p] = make_float2(v.x, v.y);
            }
        } else {
#pragma unroll
            for (int cl = 0; cl < 8; ++cl) {
                const int c = c0 + cl;
                if (c < RING || c >= RING + TOUT) continue;
                const int gc = ox + c;
                if (gc >= HW) continue;
                float v = res[i][cl >> 1][cl & 1];
                if (LAST) v = (v + 1.0f) * 0.5f;
                sout[img + (size_t)gr * HW + gc] = v;
            }
        }
    }
}

extern "C" void kernel_launch(void* const* d_in, const int* in_sizes, int n_in,
                              void* d_out, int out_size, void* d_ws, size_t ws_size,
                              hipStream_t stream) {
    const float* x = (const float*)d_in[0];
    const float* wA = (const float*)d_in[1];
    const float* wB = (const float*)d_in[2];
    const float* bias = (const float*)d_in[3];
    float* out = (float*)d_out;
    unsigned* mm = (unsigned*)d_ws;
    float* pong = (float*)((char*)d_ws + 1024);  // 128 MiB f32 buffer

    mm_init<<<1, 1, 0, stream>>>(mm);
    mm_reduce<<<2048, 256, 0, stream>>>((const float4*)x, mm, (int)(NELEM / 4));

    dim3 grid(NB, NB, NIMG);
    // steps 1-7: zeros -> out (scratch); 8-14: out -> pong; 15-21: pong -> out
    fused_k<1, 0><<<grid, 512, 0, stream>>>(x, nullptr, out, mm, wA, wB, bias);
    fused_k<0, 0><<<grid, 512, 0, stream>>>(x, out, pong, mm, wA, wB, bias);
    fused_k<0, 1><<<grid, 512, 0, stream>>>(x, pong, out, mm, wA, wB, bias);
}

// Round 8
// 1354.957 us; speedup vs baseline: 1.8384x; 1.8384x over previous
//
#include <hip/hip_runtime.h>

#define HW 1024
#define NIMG 32
#define IMGPX ((size_t)HW * HW)
#define NELEM (NIMG * IMGPX)

typedef float f2 __attribute__((ext_vector_type(2)));

// region 128x128 per block, ring 6 -> out 116x116
#define RING 6
#define TOUT 116
#define NB 9
#define LSTR 136   // words per LDS row slot; col c(0..127)->word c; col -1 ->130; col 128 ->131
#define SLOTS 66   // boundary rows: -1, {0,3 mod 4}, 128

// ---- float <-> order-preserving unsigned (for atomic min/max) ----
__device__ __forceinline__ unsigned f2su(float f) {
    unsigned u = __float_as_uint(f);
    return (u & 0x80000000u) ? ~u : (u | 0x80000000u);
}
__device__ __forceinline__ float s2f(unsigned u) {
    return __uint_as_float((u & 0x80000000u) ? (u & 0x7fffffffu) : ~u);
}

__global__ void mm_init(unsigned* mm) {
    mm[0] = 0xFFFFFFFFu;
    mm[1] = 0u;
}

__global__ __launch_bounds__(256) void mm_reduce(const float4* __restrict__ x,
                                                 unsigned* mm, int n4) {
    const int tid = threadIdx.x;
    int gid = blockIdx.x * blockDim.x + tid;
    const int stride = gridDim.x * blockDim.x;
    float vmin = 3.4e38f, vmax = -3.4e38f;
    for (int i = gid; i < n4; i += stride) {
        float4 v = x[i];
        vmin = fminf(vmin, fminf(fminf(v.x, v.y), fminf(v.z, v.w)));
        vmax = fmaxf(vmax, fmaxf(fmaxf(v.x, v.y), fmaxf(v.z, v.w)));
    }
    __shared__ float smin[256];
    __shared__ float smax[256];
    smin[tid] = vmin; smax[tid] = vmax;
    __syncthreads();
    for (int s = 128; s > 0; s >>= 1) {
        if (tid < s) {
            smin[tid] = fminf(smin[tid], smin[tid + s]);
            smax[tid] = fmaxf(smax[tid], smax[tid + s]);
        }
        __syncthreads();
    }
    if (tid == 0) {
        atomicMin(&mm[0], f2su(smin[0]));
        atomicMax(&mm[1], f2su(smax[0]));
    }
}

struct RowW { f2 P[4]; float L, R; };

// slot index for boundary row r in {-1, 0,3,4,7,...,124,127, 128}
__device__ __forceinline__ int bslot(int r) {
    return (r == -1) ? 0 : ((r == 128) ? 65 : ((r >> 2) * 2 + 1 + (((r & 3) == 3) ? 1 : 0)));
}

// 512 threads: tx 0..15 owns 8 cols (4 f2 pairs), tyg 0..31 owns 4 rows.
// State in registers; LDS = 66 boundary-row slots (36 KB) reused for xn half-tiles.
// NOTE: plain launch_bounds — round 7's (512,6) forced VGPR<=40 and spilled
// ~3.4 GB/dispatch to scratch (FETCH 1.8 GB). Unconstrained compiles ~80 VGPR
// -> 6 waves/SIMD cap -> 3 blocks/CU with 36 KB LDS.
template <int FIRST, int LAST>
__global__ __launch_bounds__(512) void fused_k(
    const float* __restrict__ x, const float* __restrict__ sin_,
    float* __restrict__ sout, const unsigned* __restrict__ mm,
    const float* __restrict__ wAp, const float* __restrict__ wBp,
    const float* __restrict__ biasp) {
#pragma clang fp contract(off)
    __shared__ float sb[SLOTS * LSTR];
    const int tid = threadIdx.x;
    const int tx = tid & 15;
    const int tyg = tid >> 4;
    const int lane = tid & 63;
    const int laneL = (lane + 63) & 63;
    const int laneR = (lane + 1) & 63;
    const int r0 = tyg << 2;
    const int c0 = tx << 3;
    const int ox = (int)blockIdx.x * TOUT - RING;
    const int oy = (int)blockIdx.y * TOUT - RING;
    const size_t img = (size_t)blockIdx.z * IMGPX;
    const bool edgeX = (blockIdx.x == 0) | (blockIdx.x == NB - 1);

    const float xmin = s2f(mm[0]);
    const float xmax = s2f(mm[1]);
    const float scale = 2.0f / (xmax - xmin);
    const float b = biasp[0];

    // aligned b128x2 + shfl row loader from an LDS slot
    auto ldSlot = [&](int slot) -> RowW {
        RowW o;
        const int base = slot * LSTR;
        const float4 q0 = *reinterpret_cast<const float4*>(&sb[base + c0]);
        const float4 q1 = *reinterpret_cast<const float4*>(&sb[base + c0 + 4]);
        o.P[0] = f2{q0.x, q0.y}; o.P[1] = f2{q0.z, q0.w};
        o.P[2] = f2{q1.x, q1.y}; o.P[3] = f2{q1.z, q1.w};
        const float fromL = __shfl(q1.w, laneL);
        const float fromR = __shfl(q0.x, laneR);
        o.L = (tx == 0) ? sb[base + 130] : fromL;
        o.R = (tx == 15) ? sb[base + 131] : fromR;
        return o;
    };

    float cf[9];
    // 9-term sequential row-major conv for pixel pair p (exact numpy order per element)
    auto conv9 = [&](const RowW& A, const RowW& B, const RowW& C, int p) -> f2 {
#pragma clang fp contract(off)
        f2 acc = f2{0.0f, 0.0f};
        f2 tl, tr;
        tl = f2{(p == 0) ? A.L : A.P[p - 1].y, A.P[p].x};
        tr = f2{A.P[p].y, (p == 3) ? A.R : A.P[p + 1].x};
        acc = acc + f2{cf[0], cf[0]} * tl;
        acc = acc + f2{cf[1], cf[1]} * A.P[p];
        acc = acc + f2{cf[2], cf[2]} * tr;
        tl = f2{(p == 0) ? B.L : B.P[p - 1].y, B.P[p].x};
        tr = f2{B.P[p].y, (p == 3) ? B.R : B.P[p + 1].x};
        acc = acc + f2{cf[3], cf[3]} * tl;
        acc = acc + f2{cf[4], cf[4]} * B.P[p];
        acc = acc + f2{cf[5], cf[5]} * tr;
        tl = f2{(p == 0) ? C.L : C.P[p - 1].y, C.P[p].x};
        tr = f2{C.P[p].y, (p == 3) ? C.R : C.P[p + 1].x};
        acc = acc + f2{cf[6], cf[6]} * tl;
        acc = acc + f2{cf[7], cf[7]} * C.P[p];
        acc = acc + f2{cf[8], cf[8]} * tr;
        return acc;
    };

    // stage 66 consecutive xn rows (starting at region row row0s) into slots 0..65
    auto stageXn = [&](int row0s) {
        for (int k = tid; k < SLOTS * 130; k += 512) {
            const int si = k / 130;
            const int ci = k - si * 130;
            const int cc = ci - 1;
            const int w = (cc == -1) ? 130 : ((cc == 128) ? 131 : cc);
            const int gr = oy + row0s + si;
            const int gc = ox + cc;
            float v = 0.0f;
            if (gr >= 0 && gr < HW && gc >= 0 && gc < HW)
                v = (x[img + (size_t)gr * HW + gc] - xmin) * scale - 1.0f;
            sb[si * LSTR + w] = v;
        }
    };

    // ---- phase 1+2: BU = conv(xn, B) via two xn half-tiles through LDS ----
#pragma unroll
    for (int i = 0; i < 9; ++i) cf[i] = wBp[i];
    f2 bu[4][4];
    {
        stageXn(-1);          // rows -1..64 -> slot = r + 1
        __syncthreads();
        if (tyg < 16) {       // rows r0-1..r0+4 in [-1,64]; window row r0-1+i -> slot r0+i
            RowW ra = ldSlot(r0), rb = ldSlot(r0 + 1);
#pragma unroll
            for (int i = 0; i < 4; ++i) {
                RowW rc = ldSlot(r0 + 2 + i);
#pragma unroll
                for (int p = 0; p < 4; ++p) bu[i][p] = conv9(ra, rb, rc, p);
                ra = rb; rb = rc;
            }
        }
        __syncthreads();
        stageXn(63);          // rows 63..128 -> slot = r - 63
        __syncthreads();
        if (tyg >= 16) {      // window row r0-1+i -> slot r0-64+i
            const int s0 = r0 - 64;
            RowW ra = ldSlot(s0), rb = ldSlot(s0 + 1);
#pragma unroll
            for (int i = 0; i < 4; ++i) {
                RowW rc = ldSlot(s0 + 2 + i);
#pragma unroll
                for (int p = 0; p < 4; ++p) bu[i][p] = conv9(ra, rb, rc, p);
                ra = rb; rb = rc;
            }
        }
        __syncthreads();
    }

    // ---- phase 3: stage s into registers + boundary slots ----
    f2 res[4][4];
    float hL[4], hR[4];
    // slot halo fill: rows -1 & 128 full width (260 items) + cols -1/128 of rows 0,3 mod 4 (128 items)
    for (int k = tid; k < 388; k += 512) {
        int rr, cc;
        if (k < 260) { rr = (k < 130) ? -1 : 128; cc = (k % 130) - 1; }
        else {
            const int kk = k - 260;
            const int s = (kk >> 1) + 1;  // 1..64
            rr = (s & 1) ? (((s - 1) >> 1) << 2) : ((((s - 2) >> 1) << 2) + 3);
            cc = (kk & 1) ? 128 : -1;
        }
        const int w = (cc == -1) ? 130 : ((cc == 128) ? 131 : cc);
        float v = 0.0f;
        if (!FIRST) {
            const int gr = oy + rr, gc = ox + cc;
            if (gr >= 0 && gr < HW && gc >= 0 && gc < HW)
                v = sin_[img + (size_t)gr * HW + gc];
        }
        sb[bslot(rr) * LSTR + w] = v;
    }
    if (FIRST) {
#pragma unroll
        for (int i = 0; i < 4; ++i) {
            hL[i] = 0.0f; hR[i] = 0.0f;
#pragma unroll
            for (int p = 0; p < 4; ++p) res[i][p] = f2{0.0f, 0.0f};
        }
    } else {
#pragma unroll
        for (int i = 0; i < 4; ++i) {
            const int gr = oy + r0 + i;
            const bool rin = (gr >= 0) & (gr < HW);
            if (!edgeX && rin) {
                const float2* src = reinterpret_cast<const float2*>(&sin_[img + (size_t)gr * HW + ox + c0]);
#pragma unroll
                for (int p = 0; p < 4; ++p) { const float2 t = src[p]; res[i][p] = f2{t.x, t.y}; }
            } else {
#pragma unroll
                for (int cl = 0; cl < 8; ++cl) {
                    const int gc = ox + c0 + cl;
                    float v = 0.0f;
                    if (rin && gc >= 0 && gc < HW) v = sin_[img + (size_t)gr * HW + gc];
                    res[i][cl >> 1][cl & 1] = v;
                }
            }
            const int gcl = ox - 1, gcr = ox + 128;
            hL[i] = (rin && gcl >= 0) ? sin_[img + (size_t)gr * HW + gcl] : 0.0f;
            hR[i] = (rin && gcr < HW) ? sin_[img + (size_t)gr * HW + gcr] : 0.0f;
        }
    }

    auto wrRow = [&](int i, int slot) {
        const int base = slot * LSTR + c0;
        *reinterpret_cast<float4*>(&sb[base]) =
            make_float4(res[i][0].x, res[i][0].y, res[i][1].x, res[i][1].y);
        *reinterpret_cast<float4*>(&sb[base + 4]) =
            make_float4(res[i][2].x, res[i][2].y, res[i][3].x, res[i][3].y);
    };
    wrRow(0, 2 * tyg + 1); wrRow(3, 2 * tyg + 2);
    __syncthreads();

    // ---- phase 4: 7 fused steps, state in registers ----
#pragma unroll
    for (int i = 0; i < 9; ++i) cf[i] = wAp[i];
    const f2 b2 = f2{b, b};
    f2 mR2[4], mC2[4];
#pragma unroll
    for (int i = 0; i < 4; ++i) {
        const int g = oy + r0 + i;
        const float m = (g >= 0 && g < HW) ? 1.0f : 0.0f;
        mR2[i] = f2{m, m};
    }
#pragma unroll
    for (int p = 0; p < 4; ++p) {
        const int g0 = ox + c0 + 2 * p, g1 = g0 + 1;
        mC2[p] = f2{(g0 >= 0 && g0 < HW) ? 1.0f : 0.0f,
                    (g1 >= 0 && g1 < HW) ? 1.0f : 0.0f};
    }

    const int slotM1 = (tyg == 0) ? 0 : 2 * tyg;
    const int slotP4 = (tyg == 31) ? 65 : 2 * tyg + 3;

#pragma unroll 1
    for (int t = 0; t < 7; ++t) {
        const RowW m1 = ldSlot(slotM1);
        const RowW p4 = ldSlot(slotP4);
        __syncthreads();  // all reads of old boundary rows complete

        RowW o[4];
#pragma unroll
        for (int i = 0; i < 4; ++i) {
            o[i].P[0] = res[i][0]; o[i].P[1] = res[i][1];
            o[i].P[2] = res[i][2]; o[i].P[3] = res[i][3];
            const float fromL = __shfl(res[i][3].y, laneL);
            const float fromR = __shfl(res[i][0].x, laneR);
            o[i].L = (tx == 0) ? hL[i] : fromL;
            o[i].R = (tx == 15) ? hR[i] : fromR;
        }
        f2 nw[4][4];
#pragma unroll
        for (int i = 0; i < 4; ++i) {
            const RowW& A = (i == 0) ? m1 : o[i - 1];
            const RowW& B = o[i];
            const RowW& C = (i == 3) ? p4 : o[i + 1];
#pragma unroll
            for (int p = 0; p < 4; ++p) {
                f2 v = conv9(A, B, C, p);
                v = (v + b2) + bu[i][p];
                v = __builtin_elementwise_max(v, f2{-1.0f, -1.0f});
                v = __builtin_elementwise_min(v, f2{1.0f, 1.0f});
                v = v * mR2[i];
                v = v * mC2[p];
                nw[i][p] = v;
            }
        }
#pragma unroll
        for (int i = 0; i < 4; ++i)
#pragma unroll
            for (int p = 0; p < 4; ++p) res[i][p] = nw[i][p];
        wrRow(0, 2 * tyg + 1); wrRow(3, 2 * tyg + 2);
        __syncthreads();  // new boundary rows visible
    }

    // ---- phase 5: store inner 116x116 tile ----
#pragma unroll
    for (int i = 0; i < 4; ++i) {
        const int r = r0 + i;
        if (r < RING || r >= RING + TOUT) continue;
        const int gr = oy + r;
        if (gr >= HW) continue;
        if (!edgeX && tx >= 1 && tx <= 14) {
            float2* dst = reinterpret_cast<float2*>(&sout[img + (size_t)gr * HW + ox + c0]);
#pragma unroll
            for (int p = 0; p < 4; ++p) {
                f2 v = res[i][p];
                if (LAST) v = (v + f2{1.0f, 1.0f}) * f2{0.5f, 0.5f};
                dst[p] = make_float2(v.x, v.y);
            }
        } else {
#pragma unroll
            for (int cl = 0; cl < 8; ++cl) {
                const int c = c0 + cl;
                if (c < RING || c >= RING + TOUT) continue;
                const int gc = ox + c;
                if (gc >= HW) continue;
                float v = res[i][cl >> 1][cl & 1];
                if (LAST) v = (v + 1.0f) * 0.5f;
                sout[img + (size_t)gr * HW + gc] = v;
            }
        }
    }
}

extern "C" void kernel_launch(void* const* d_in, const int* in_sizes, int n_in,
                              void* d_out, int out_size, void* d_ws, size_t ws_size,
                              hipStream_t stream) {
    const float* x = (const float*)d_in[0];
    const float* wA = (const float*)d_in[1];
    const float* wB = (const float*)d_in[2];
    const float* bias = (const float*)d_in[3];
    float* out = (float*)d_out;
    unsigned* mm = (unsigned*)d_ws;
    float* pong = (float*)((char*)d_ws + 1024);  // 128 MiB f32 buffer

    mm_init<<<1, 1, 0, stream>>>(mm);
    mm_reduce<<<2048, 256, 0, stream>>>((const float4*)x, mm, (int)(NELEM / 4));

    dim3 grid(NB, NB, NIMG);
    // steps 1-7: zeros -> out (scratch); 8-14: out -> pong; 15-21: pong -> out
    fused_k<1, 0><<<grid, 512, 0, stream>>>(x, nullptr, out, mm, wA, wB, bias);
    fused_k<0, 0><<<grid, 512, 0, stream>>>(x, out, pong, mm, wA, wB, bias);
    fused_k<0, 1><<<grid, 512, 0, stream>>>(x, pong, out, mm, wA, wB, bias);
}

// Round 9
// 1055.184 us; speedup vs baseline: 2.3606x; 1.2841x over previous
//
#include <hip/hip_runtime.h>

#define HW 1024
#define NIMG 32
#define IMGPX ((size_t)HW * HW)
#define NELEM (NIMG * IMGPX)

typedef float f2 __attribute__((ext_vector_type(2)));

// region 128x128 per block, ring 6 -> out 116x116
#define RING 6
#define TOUT 116
#define NB 9
#define LSTR 136    // words per slot; col c(0..127)->word c; col -1 ->130; col 128 ->131
#define SLOTS 66    // boundary rows: -1, {0,3 mod 4}, 128
#define BUFW (SLOTS * LSTR)

// ---- float <-> order-preserving unsigned (for atomic min/max) ----
__device__ __forceinline__ unsigned f2su(float f) {
    unsigned u = __float_as_uint(f);
    return (u & 0x80000000u) ? ~u : (u | 0x80000000u);
}
__device__ __forceinline__ float s2f(unsigned u) {
    return __uint_as_float((u & 0x80000000u) ? (u & 0x7fffffffu) : ~u);
}

__global__ void mm_init(unsigned* mm) {
    mm[0] = 0xFFFFFFFFu;
    mm[1] = 0u;
}

__global__ __launch_bounds__(256) void mm_reduce(const float4* __restrict__ x,
                                                 unsigned* mm, int n4) {
    const int tid = threadIdx.x;
    int gid = blockIdx.x * blockDim.x + tid;
    const int stride = gridDim.x * blockDim.x;
    float vmin = 3.4e38f, vmax = -3.4e38f;
    for (int i = gid; i < n4; i += stride) {
        float4 v = x[i];
        vmin = fminf(vmin, fminf(fminf(v.x, v.y), fminf(v.z, v.w)));
        vmax = fmaxf(vmax, fmaxf(fmaxf(v.x, v.y), fmaxf(v.z, v.w)));
    }
    __shared__ float smin[256];
    __shared__ float smax[256];
    smin[tid] = vmin; smax[tid] = vmax;
    __syncthreads();
    for (int s = 128; s > 0; s >>= 1) {
        if (tid < s) {
            smin[tid] = fminf(smin[tid], smin[tid + s]);
            smax[tid] = fmaxf(smax[tid], smax[tid + s]);
        }
        __syncthreads();
    }
    if (tid == 0) {
        atomicMin(&mm[0], f2su(smin[0]));
        atomicMax(&mm[1], f2su(smax[0]));
    }
}

struct RowW { f2 P[2]; float L, R; };

// slot index for boundary row r in {-1, 0,3,4,7,...,124,127, 128}
__device__ __forceinline__ int bslot(int r) {
    return (r == -1) ? 0 : ((r == 128) ? 65 : ((r >> 2) * 2 + 1 + (((r & 3) == 3) ? 1 : 0)));
}

// 1024 threads: tx 0..31 owns 4 cols (2 f2 pairs), tyg 0..31 owns 4 rows.
// State in registers; double-buffered boundary slots (2 x 36 KB LDS) -> one
// barrier per step. VGPR target <= 64 (occupancy cliff, m69).
template <int FIRST, int LAST>
__global__ __launch_bounds__(1024) void fused_k(
    const float* __restrict__ x, const float* __restrict__ sin_,
    float* __restrict__ sout, const unsigned* __restrict__ mm,
    const float* __restrict__ wAp, const float* __restrict__ wBp,
    const float* __restrict__ biasp) {
#pragma clang fp contract(off)
    __shared__ float sb[2 * BUFW];
    const int tid = threadIdx.x;
    const int tx = tid & 31;
    const int tyg = tid >> 5;
    const int lane = tid & 63;
    const int laneL = (lane + 63) & 63;
    const int laneR = (lane + 1) & 63;
    const int r0 = tyg << 2;
    const int c0 = tx << 2;
    const int ox = (int)blockIdx.x * TOUT - RING;
    const int oy = (int)blockIdx.y * TOUT - RING;
    const size_t img = (size_t)blockIdx.z * IMGPX;
    const bool edgeX = (blockIdx.x == 0) | (blockIdx.x == NB - 1);

    const float xmin = s2f(mm[0]);
    const float xmax = s2f(mm[1]);
    const float scale = 2.0f / (xmax - xmin);
    const float b = biasp[0];

    // aligned b128 + shfl row loader from a slot of buffer at word offset bo
    auto ldSlot = [&](int bo, int slot) -> RowW {
        RowW o;
        const int base = bo + slot * LSTR;
        const float4 q0 = *reinterpret_cast<const float4*>(&sb[base + c0]);
        o.P[0] = f2{q0.x, q0.y}; o.P[1] = f2{q0.z, q0.w};
        const float fromL = __shfl(q0.w, laneL);
        const float fromR = __shfl(q0.x, laneR);
        o.L = (tx == 0) ? sb[base + 130] : fromL;
        o.R = (tx == 31) ? sb[base + 131] : fromR;
        return o;
    };

    float cf[9];
    // 9-term sequential row-major conv for pixel pair p in {0,1} (exact numpy order)
    auto conv9 = [&](const RowW& A, const RowW& B, const RowW& C, int p) -> f2 {
#pragma clang fp contract(off)
        f2 acc = f2{0.0f, 0.0f};
        f2 tl, tr;
        tl = f2{(p == 0) ? A.L : A.P[0].y, A.P[p].x};
        tr = f2{A.P[p].y, (p == 0) ? A.P[1].x : A.R};
        acc = acc + f2{cf[0], cf[0]} * tl;
        acc = acc + f2{cf[1], cf[1]} * A.P[p];
        acc = acc + f2{cf[2], cf[2]} * tr;
        tl = f2{(p == 0) ? B.L : B.P[0].y, B.P[p].x};
        tr = f2{B.P[p].y, (p == 0) ? B.P[1].x : B.R};
        acc = acc + f2{cf[3], cf[3]} * tl;
        acc = acc + f2{cf[4], cf[4]} * B.P[p];
        acc = acc + f2{cf[5], cf[5]} * tr;
        tl = f2{(p == 0) ? C.L : C.P[0].y, C.P[p].x};
        tr = f2{C.P[p].y, (p == 0) ? C.P[1].x : C.R};
        acc = acc + f2{cf[6], cf[6]} * tl;
        acc = acc + f2{cf[7], cf[7]} * C.P[p];
        acc = acc + f2{cf[8], cf[8]} * tr;
        return acc;
    };

    // stage 66 consecutive xn rows (starting at region row row0s) into buffer 0
    auto stageXn = [&](int row0s) {
        for (int k = tid; k < SLOTS * 130; k += 1024) {
            const int si = k / 130;
            const int ci = k - si * 130;
            const int cc = ci - 1;
            const int w = (cc == -1) ? 130 : ((cc == 128) ? 131 : cc);
            const int gr = oy + row0s + si;
            const int gc = ox + cc;
            float v = 0.0f;
            if (gr >= 0 && gr < HW && gc >= 0 && gc < HW)
                v = (x[img + (size_t)gr * HW + gc] - xmin) * scale - 1.0f;
            sb[si * LSTR + w] = v;
        }
    };

    // ---- phase 1+2: BU = conv(xn, B) via two xn half-tiles through buffer 0 ----
#pragma unroll
    for (int i = 0; i < 9; ++i) cf[i] = wBp[i];
    f2 bu[4][2];
    {
        stageXn(-1);          // region row r -> slot r+1 (rows -1..64)
        __syncthreads();
        if (tyg < 16) {
            RowW prev = ldSlot(0, r0);      // row r0-1
            RowW cur = ldSlot(0, r0 + 1);   // row r0
#pragma unroll
            for (int i = 0; i < 4; ++i) {
                RowW nxt = ldSlot(0, r0 + 2 + i);
                bu[i][0] = conv9(prev, cur, nxt, 0);
                bu[i][1] = conv9(prev, cur, nxt, 1);
                prev = cur; cur = nxt;
            }
        }
        __syncthreads();
        stageXn(63);          // region row r -> slot r-63 (rows 63..128)
        __syncthreads();
        if (tyg >= 16) {
            const int s0 = r0 - 64;
            RowW prev = ldSlot(0, s0);
            RowW cur = ldSlot(0, s0 + 1);
#pragma unroll
            for (int i = 0; i < 4; ++i) {
                RowW nxt = ldSlot(0, s0 + 2 + i);
                bu[i][0] = conv9(prev, cur, nxt, 0);
                bu[i][1] = conv9(prev, cur, nxt, 1);
                prev = cur; cur = nxt;
            }
        }
        __syncthreads();
    }

    // ---- phase 3: stage s into registers + frozen halos into BOTH buffers ----
    f2 res[4][2];
    float hS[4];  // tx==0 lanes: left halo; tx==31 lanes: right halo; else unused
    // frozen halo: rows -1 & 128 (260 items) + cols -1/128 of boundary rows (128)
    for (int k = tid; k < 388; k += 1024) {
        int rr, cc;
        if (k < 260) { rr = (k < 130) ? -1 : 128; cc = (k % 130) - 1; }
        else {
            const int kk = k - 260;
            const int s = (kk >> 1) + 1;  // 1..64
            rr = (s & 1) ? (((s - 1) >> 1) << 2) : ((((s - 2) >> 1) << 2) + 3);
            cc = (kk & 1) ? 128 : -1;
        }
        const int w = (cc == -1) ? 130 : ((cc == 128) ? 131 : cc);
        float v = 0.0f;
        if (!FIRST) {
            const int gr = oy + rr, gc = ox + cc;
            if (gr >= 0 && gr < HW && gc >= 0 && gc < HW)
                v = sin_[img + (size_t)gr * HW + gc];
        }
        const int wo = bslot(rr) * LSTR + w;
        sb[wo] = v;
        sb[BUFW + wo] = v;
    }
    if (FIRST) {
#pragma unroll
        for (int i = 0; i < 4; ++i) {
            hS[i] = 0.0f;
            res[i][0] = f2{0.0f, 0.0f};
            res[i][1] = f2{0.0f, 0.0f};
        }
    } else {
#pragma unroll
        for (int i = 0; i < 4; ++i) {
            const int gr = oy + r0 + i;
            const bool rin = (gr >= 0) & (gr < HW);
            if (!edgeX && rin) {
                const float2* src = reinterpret_cast<const float2*>(&sin_[img + (size_t)gr * HW + ox + c0]);
                const float2 t0 = src[0];
                const float2 t1 = src[1];
                res[i][0] = f2{t0.x, t0.y};
                res[i][1] = f2{t1.x, t1.y};
            } else {
#pragma unroll
                for (int cl = 0; cl < 4; ++cl) {
                    const int gc = ox + c0 + cl;
                    float v = 0.0f;
                    if (rin && gc >= 0 && gc < HW) v = sin_[img + (size_t)gr * HW + gc];
                    res[i][cl >> 1][cl & 1] = v;
                }
            }
            float hv = 0.0f;
            if (tx == 0) {
                const int gc = ox - 1;
                if (rin && gc >= 0) hv = sin_[img + (size_t)gr * HW + gc];
            } else if (tx == 31) {
                const int gc = ox + 128;
                if (rin && gc < HW) hv = sin_[img + (size_t)gr * HW + gc];
            }
            hS[i] = hv;
        }
    }

    auto wrRow = [&](int bo, int i, int slot) {
        *reinterpret_cast<float4*>(&sb[bo + slot * LSTR + c0]) =
            make_float4(res[i][0].x, res[i][0].y, res[i][1].x, res[i][1].y);
    };
    wrRow(0, 0, 2 * tyg + 1);
    wrRow(0, 3, 2 * tyg + 2);
    __syncthreads();

    // ---- phase 4: 7 fused steps, one barrier each (double-buffered slots) ----
#pragma unroll
    for (int i = 0; i < 9; ++i) cf[i] = wAp[i];
    float mR[4];
#pragma unroll
    for (int i = 0; i < 4; ++i) {
        const int g = oy + r0 + i;
        mR[i] = (g >= 0 && g < HW) ? 1.0f : 0.0f;
    }
    f2 mC2[2];
#pragma unroll
    for (int p = 0; p < 2; ++p) {
        const int g0 = ox + c0 + 2 * p, g1 = g0 + 1;
        mC2[p] = f2{(g0 >= 0 && g0 < HW) ? 1.0f : 0.0f,
                    (g1 >= 0 && g1 < HW) ? 1.0f : 0.0f};
    }

    auto buildRow = [&](const f2 pr[2], float hs) -> RowW {
        RowW o;
        o.P[0] = pr[0]; o.P[1] = pr[1];
        const float fromL = __shfl(pr[1].y, laneL);
        const float fromR = __shfl(pr[0].x, laneR);
        o.L = (tx == 0) ? hs : fromL;
        o.R = (tx == 31) ? hs : fromR;
        return o;
    };

    const int slotM1 = (tyg == 0) ? 0 : 2 * tyg;
    const int slotP4 = (tyg == 31) ? 65 : 2 * tyg + 3;

#pragma unroll 1
    for (int t = 0; t < 7; ++t) {
        const int rdo = (t & 1) * BUFW;
        const int wro = BUFW - rdo;
        RowW prev = ldSlot(rdo, slotM1);      // old row r0-1
        RowW cur = buildRow(res[0], hS[0]);
#pragma unroll
        for (int i = 0; i < 4; ++i) {
            RowW nxt = (i < 3) ? buildRow(res[i + 1], hS[i + 1])
                               : ldSlot(rdo, slotP4);  // old row r0+4
            f2 n0 = conv9(prev, cur, nxt, 0);
            f2 n1 = conv9(prev, cur, nxt, 1);
            n0 = (n0 + f2{b, b}) + bu[i][0];
            n1 = (n1 + f2{b, b}) + bu[i][1];
            n0 = __builtin_elementwise_max(n0, f2{-1.0f, -1.0f});
            n0 = __builtin_elementwise_min(n0, f2{1.0f, 1.0f});
            n1 = __builtin_elementwise_max(n1, f2{-1.0f, -1.0f});
            n1 = __builtin_elementwise_min(n1, f2{1.0f, 1.0f});
            n0 = n0 * f2{mR[i], mR[i]};
            n1 = n1 * f2{mR[i], mR[i]};
            n0 = n0 * mC2[0];
            n1 = n1 * mC2[1];
            prev = cur; cur = nxt;
            res[i][0] = n0; res[i][1] = n1;
        }
        wrRow(wro, 0, 2 * tyg + 1);
        wrRow(wro, 3, 2 * tyg + 2);
        __syncthreads();
    }

    // ---- phase 5: store inner 116x116 tile ----
    const bool fullc = (!edgeX) && (c0 >= RING) && (c0 + 3 < RING + TOUT);
#pragma unroll
    for (int i = 0; i < 4; ++i) {
        const int r = r0 + i;
        if (r < RING || r >= RING + TOUT) continue;
        const int gr = oy + r;
        if (gr >= HW) continue;  // gr >= 0 guaranteed
        if (fullc) {
            float2* dst = reinterpret_cast<float2*>(&sout[img + (size_t)gr * HW + ox + c0]);
            f2 v0 = res[i][0], v1 = res[i][1];
            if (LAST) {
                v0 = (v0 + f2{1.0f, 1.0f}) * f2{0.5f, 0.5f};
                v1 = (v1 + f2{1.0f, 1.0f}) * f2{0.5f, 0.5f};
            }
            dst[0] = make_float2(v0.x, v0.y);
            dst[1] = make_float2(v1.x, v1.y);
        } else {
#pragma unroll
            for (int cl = 0; cl < 4; ++cl) {
                const int c = c0 + cl;
                if (c < RING || c >= RING + TOUT) continue;
                const int gc = ox + c;
                if (gc < 0 || gc >= HW) continue;
                float v = res[i][cl >> 1][cl & 1];
                if (LAST) v = (v + 1.0f) * 0.5f;
                sout[img + (size_t)gr * HW + gc] = v;
            }
        }
    }
}

extern "C" void kernel_launch(void* const* d_in, const int* in_sizes, int n_in,
                              void* d_out, int out_size, void* d_ws, size_t ws_size,
                              hipStream_t stream) {
    const float* x = (const float*)d_in[0];
    const float* wA = (const float*)d_in[1];
    const float* wB = (const float*)d_in[2];
    const float* bias = (const float*)d_in[3];
    float* out = (float*)d_out;
    unsigned* mm = (unsigned*)d_ws;
    float* pong = (float*)((char*)d_ws + 1024);  // 128 MiB f32 buffer

    mm_init<<<1, 1, 0, stream>>>(mm);
    mm_reduce<<<2048, 256, 0, stream>>>((const float4*)x, mm, (int)(NELEM / 4));

    dim3 grid(NB, NB, NIMG);
    // steps 1-7: zeros -> out (scratch); 8-14: out -> pong; 15-21: pong -> out
    fused_k<1, 0><<<grid, 1024, 0, stream>>>(x, nullptr, out, mm, wA, wB, bias);
    fused_k<0, 0><<<grid, 1024, 0, stream>>>(x, out, pong, mm, wA, wB, bias);
    fused_k<0, 1><<<grid, 1024, 0, stream>>>(x, pong, out, mm, wA, wB, bias);
}

// Round 10
// 796.624 us; speedup vs baseline: 3.1268x; 1.3246x over previous
//
#include <hip/hip_runtime.h>

#define HW 1024
#define NIMG 32
#define IMGPX ((size_t)HW * HW)
#define NELEM (NIMG * IMGPX)

typedef float f2 __attribute__((ext_vector_type(2)));

// region 128x64 per block, ring 6 -> out 116x52
#define RING 6
#define TOX 116
#define TOY 52
#define NBX 9
#define NBY 20
#define LSTR 136    // words per slot; col c(0..127)->word c; col -1 ->130; col 128 ->131
#define SLOTS 34    // boundary rows per buffer: -1, {0,3 mod 4}x16, 64
#define BUFW (SLOTS * LSTR)

// ---- float <-> order-preserving unsigned (for atomic min/max) ----
__device__ __forceinline__ unsigned f2su(float f) {
    unsigned u = __float_as_uint(f);
    return (u & 0x80000000u) ? ~u : (u | 0x80000000u);
}
__device__ __forceinline__ float s2f(unsigned u) {
    return __uint_as_float((u & 0x80000000u) ? (u & 0x7fffffffu) : ~u);
}

__global__ void mm_init(unsigned* mm) {
    mm[0] = 0xFFFFFFFFu;
    mm[1] = 0u;
}

__global__ __launch_bounds__(256) void mm_reduce(const float4* __restrict__ x,
                                                 unsigned* mm, int n4) {
    const int tid = threadIdx.x;
    int gid = blockIdx.x * blockDim.x + tid;
    const int stride = gridDim.x * blockDim.x;
    float vmin = 3.4e38f, vmax = -3.4e38f;
    for (int i = gid; i < n4; i += stride) {
        float4 v = x[i];
        vmin = fminf(vmin, fminf(fminf(v.x, v.y), fminf(v.z, v.w)));
        vmax = fmaxf(vmax, fmaxf(fmaxf(v.x, v.y), fmaxf(v.z, v.w)));
    }
    __shared__ float smin[256];
    __shared__ float smax[256];
    smin[tid] = vmin; smax[tid] = vmax;
    __syncthreads();
    for (int s = 128; s > 0; s >>= 1) {
        if (tid < s) {
            smin[tid] = fminf(smin[tid], smin[tid + s]);
            smax[tid] = fmaxf(smax[tid], smax[tid + s]);
        }
        __syncthreads();
    }
    if (tid == 0) {
        atomicMin(&mm[0], f2su(smin[0]));
        atomicMax(&mm[1], f2su(smax[0]));
    }
}

struct RowW { f2 P[2]; float L, R; };

// 512 threads: tx 0..31 owns 4 cols (2 f2 pairs), tyg 0..15 owns 4 rows.
// State in registers; double-buffered boundary slots (2 x 18.5 KB LDS).
// 37 KB LDS + ~44 VGPR -> 4 blocks/CU (round 9's 72 KB allowed only 2).
template <int FIRST, int LAST>
__global__ __launch_bounds__(512) void fused_k(
    const float* __restrict__ x, const float* __restrict__ sin_,
    float* __restrict__ sout, const unsigned* __restrict__ mm,
    const float* __restrict__ wAp, const float* __restrict__ wBp,
    const float* __restrict__ biasp) {
#pragma clang fp contract(off)
    __shared__ float sb[2 * BUFW];
    const int tid = threadIdx.x;
    const int tx = tid & 31;
    const int tyg = tid >> 5;          // 0..15
    const int lane = tid & 63;
    const int laneL = (lane + 63) & 63;
    const int laneR = (lane + 1) & 63;
    const int r0 = tyg << 2;
    const int c0 = tx << 2;
    const int bx = (int)blockIdx.x, by = (int)blockIdx.y;
    const int ox = bx * TOX - RING;
    const int oy = by * TOY - RING;
    const size_t img = (size_t)blockIdx.z * IMGPX;
    const bool edgeX = (bx == 0) | (bx == NBX - 1);
    const bool edgeY = (by == 0) | (by == NBY - 1);
    const bool intr = !(edgeX | edgeY);   // whole region strictly inside image

    const float xmin = s2f(mm[0]);
    const float xmax = s2f(mm[1]);
    const float scale = 2.0f / (xmax - xmin);
    const float b = biasp[0];

    // aligned b128 + shfl row loader; `wb` is an absolute word offset of a slot
    auto ldSlot = [&](int wb) -> RowW {
        RowW o;
        const float4 q0 = *reinterpret_cast<const float4*>(&sb[wb + c0]);
        o.P[0] = f2{q0.x, q0.y}; o.P[1] = f2{q0.z, q0.w};
        const float fromL = __shfl(q0.w, laneL);
        const float fromR = __shfl(q0.x, laneR);
        o.L = (tx == 0) ? sb[wb + 130] : fromL;
        o.R = (tx == 31) ? sb[wb + 131] : fromR;
        return o;
    };

    float cf[9];
    // 9-term sequential row-major conv for pixel pair p in {0,1} (exact numpy order)
    auto conv9 = [&](const RowW& A, const RowW& B, const RowW& C, int p) -> f2 {
#pragma clang fp contract(off)
        f2 acc = f2{0.0f, 0.0f};
        f2 tl, tr;
        tl = f2{(p == 0) ? A.L : A.P[0].y, A.P[p].x};
        tr = f2{A.P[p].y, (p == 0) ? A.P[1].x : A.R};
        acc = acc + f2{cf[0], cf[0]} * tl;
        acc = acc + f2{cf[1], cf[1]} * A.P[p];
        acc = acc + f2{cf[2], cf[2]} * tr;
        tl = f2{(p == 0) ? B.L : B.P[0].y, B.P[p].x};
        tr = f2{B.P[p].y, (p == 0) ? B.P[1].x : B.R};
        acc = acc + f2{cf[3], cf[3]} * tl;
        acc = acc + f2{cf[4], cf[4]} * B.P[p];
        acc = acc + f2{cf[5], cf[5]} * tr;
        tl = f2{(p == 0) ? C.L : C.P[0].y, C.P[p].x};
        tr = f2{C.P[p].y, (p == 0) ? C.P[1].x : C.R};
        acc = acc + f2{cf[6], cf[6]} * tl;
        acc = acc + f2{cf[7], cf[7]} * C.P[p];
        acc = acc + f2{cf[8], cf[8]} * tr;
        return acc;
    };

    // ---- phase 1: xn rows -1..64 into linear slots 0..65 (spans BOTH buffers) ----
    if (intr) {
        for (int k = tid; k < 66 * 130; k += 512) {
            const int si = k / 130;
            const int cc = (k - si * 130) - 1;
            const int w = (cc == -1) ? 130 : ((cc == 128) ? 131 : cc);
            const float v =
                (x[img + (size_t)(oy + si - 1) * HW + (ox + cc)] - xmin) * scale - 1.0f;
            sb[si * LSTR + w] = v;
        }
    } else {
        for (int k = tid; k < 66 * 130; k += 512) {
            const int si = k / 130;
            const int cc = (k - si * 130) - 1;
            const int w = (cc == -1) ? 130 : ((cc == 128) ? 131 : cc);
            const int gr = oy + si - 1;
            const int gc = ox + cc;
            float v = 0.0f;
            if (gr >= 0 && gr < HW && gc >= 0 && gc < HW)
                v = (x[img + (size_t)gr * HW + gc] - xmin) * scale - 1.0f;
            sb[si * LSTR + w] = v;
        }
    }
    __syncthreads();

    // ---- phase 2: BU = conv(xn, B), all waves in one pass ----
#pragma unroll
    for (int i = 0; i < 9; ++i) cf[i] = wBp[i];
    f2 bu[4][2];
    {
        // window row r0-1+i -> slot r0+i (slot = row+1), slots r0..r0+5 <= 65
        RowW prev = ldSlot((r0) * LSTR);
        RowW cur = ldSlot((r0 + 1) * LSTR);
#pragma unroll
        for (int i = 0; i < 4; ++i) {
            RowW nxt = ldSlot((r0 + 2 + i) * LSTR);
            bu[i][0] = conv9(prev, cur, nxt, 0);
            bu[i][1] = conv9(prev, cur, nxt, 1);
            prev = cur; cur = nxt;
        }
    }
    __syncthreads();

    // ---- phase 3: stage s into registers + frozen halos into BOTH buffers ----
    // slot map (per buffer): row -1 -> 0; row 4k -> 2k+1; row 4k+3 -> 2k+2; row 64 -> 33
    f2 res[4][2];
    float hS[4];  // tx==0: left halo col; tx==31: right halo col
    for (int k = tid; k < 324; k += 512) {
        int rr, cc;
        if (k < 260) { rr = (k < 130) ? -1 : 64; cc = (k % 130) - 1; }
        else {
            const int kk = k - 260;
            const int s = kk >> 1;            // 0..31
            rr = (s & 1) ? ((s >> 1) * 4 + 3) : ((s >> 1) * 4);
            cc = (kk & 1) ? 128 : -1;
        }
        const int w = (cc == -1) ? 130 : ((cc == 128) ? 131 : cc);
        const int slot = (rr == -1) ? 0 : ((rr == 64) ? 33 : ((rr >> 2) * 2 + 1 + (((rr & 3) == 3) ? 1 : 0)));
        float v = 0.0f;
        if (!FIRST) {
            const int gr = oy + rr, gc = ox + cc;
            if (gr >= 0 && gr < HW && gc >= 0 && gc < HW)
                v = sin_[img + (size_t)gr * HW + gc];
        }
        const int wo = slot * LSTR + w;
        sb[wo] = v;
        sb[BUFW + wo] = v;
    }
    if (FIRST) {
#pragma unroll
        for (int i = 0; i < 4; ++i) {
            hS[i] = 0.0f;
            res[i][0] = f2{0.0f, 0.0f};
            res[i][1] = f2{0.0f, 0.0f};
        }
    } else if (intr) {
#pragma unroll
        for (int i = 0; i < 4; ++i) {
            const float2* src = reinterpret_cast<const float2*>(
                &sin_[img + (size_t)(oy + r0 + i) * HW + ox + c0]);
            const float2 t0 = src[0];
            const float2 t1 = src[1];
            res[i][0] = f2{t0.x, t0.y};
            res[i][1] = f2{t1.x, t1.y};
            float hv = 0.0f;
            if (tx == 0) hv = sin_[img + (size_t)(oy + r0 + i) * HW + (ox - 1)];
            else if (tx == 31) hv = sin_[img + (size_t)(oy + r0 + i) * HW + (ox + 128)];
            hS[i] = hv;
        }
    } else {
#pragma unroll
        for (int i = 0; i < 4; ++i) {
            const int gr = oy + r0 + i;
            const bool rin = (gr >= 0) & (gr < HW);
#pragma unroll
            for (int cl = 0; cl < 4; ++cl) {
                const int gc = ox + c0 + cl;
                float v = 0.0f;
                if (rin && gc >= 0 && gc < HW) v = sin_[img + (size_t)gr * HW + gc];
                res[i][cl >> 1][cl & 1] = v;
            }
            float hv = 0.0f;
            if (tx == 0) {
                const int gc = ox - 1;
                if (rin && gc >= 0) hv = sin_[img + (size_t)gr * HW + gc];
            } else if (tx == 31) {
                const int gc = ox + 128;
                if (rin && gc < HW) hv = sin_[img + (size_t)gr * HW + gc];
            }
            hS[i] = hv;
        }
    }

    auto wrRow = [&](int bo, int i, int slot) {
        *reinterpret_cast<float4*>(&sb[bo + slot * LSTR + c0]) =
            make_float4(res[i][0].x, res[i][0].y, res[i][1].x, res[i][1].y);
    };
    wrRow(0, 0, 2 * tyg + 1);
    wrRow(0, 3, 2 * tyg + 2);
    __syncthreads();

    // ---- phase 4: 7 fused steps, one barrier each (double-buffered slots) ----
#pragma unroll
    for (int i = 0; i < 9; ++i) cf[i] = wAp[i];
    float mR[4];
#pragma unroll
    for (int i = 0; i < 4; ++i) {
        const int g = oy + r0 + i;
        mR[i] = (g >= 0 && g < HW) ? 1.0f : 0.0f;
    }
    f2 mC2[2];
#pragma unroll
    for (int p = 0; p < 2; ++p) {
        const int g0 = ox + c0 + 2 * p, g1 = g0 + 1;
        mC2[p] = f2{(g0 >= 0 && g0 < HW) ? 1.0f : 0.0f,
                    (g1 >= 0 && g1 < HW) ? 1.0f : 0.0f};
    }

    auto buildRow = [&](const f2 pr[2], float hs) -> RowW {
        RowW o;
        o.P[0] = pr[0]; o.P[1] = pr[1];
        const float fromL = __shfl(pr[1].y, laneL);
        const float fromR = __shfl(pr[0].x, laneR);
        o.L = (tx == 0) ? hs : fromL;
        o.R = (tx == 31) ? hs : fromR;
        return o;
    };

    const int slotM1 = (tyg == 0) ? 0 : 2 * tyg;
    const int slotP4 = (tyg == 15) ? 33 : 2 * tyg + 3;

#pragma unroll 1
    for (int t = 0; t < 7; ++t) {
        const int rdo = (t & 1) * BUFW;
        const int wro = BUFW - rdo;
        RowW prev = ldSlot(rdo + slotM1 * LSTR);   // old row r0-1
        RowW cur = buildRow(res[0], hS[0]);
#pragma unroll
        for (int i = 0; i < 4; ++i) {
            RowW nxt = (i < 3) ? buildRow(res[i + 1], hS[i + 1])
                               : ldSlot(rdo + slotP4 * LSTR);  // old row r0+4
            f2 n0 = conv9(prev, cur, nxt, 0);
            f2 n1 = conv9(prev, cur, nxt, 1);
            n0 = (n0 + f2{b, b}) + bu[i][0];
            n1 = (n1 + f2{b, b}) + bu[i][1];
            n0 = __builtin_elementwise_max(n0, f2{-1.0f, -1.0f});
            n0 = __builtin_elementwise_min(n0, f2{1.0f, 1.0f});
            n1 = __builtin_elementwise_max(n1, f2{-1.0f, -1.0f});
            n1 = __builtin_elementwise_min(n1, f2{1.0f, 1.0f});
            if (!intr) {  // exact 0/1 masks only needed when region leaves image
                n0 = n0 * f2{mR[i], mR[i]};
                n1 = n1 * f2{mR[i], mR[i]};
                n0 = n0 * mC2[0];
                n1 = n1 * mC2[1];
            }
            prev = cur; cur = nxt;
            res[i][0] = n0; res[i][1] = n1;
        }
        wrRow(wro, 0, 2 * tyg + 1);
        wrRow(wro, 3, 2 * tyg + 2);
        __syncthreads();
    }

    // ---- phase 5: store inner 116x52 tile ----
    const bool fullc = intr && (c0 >= RING) && (c0 + 3 < RING + TOX);
#pragma unroll
    for (int i = 0; i < 4; ++i) {
        const int r = r0 + i;
        if (r < RING || r >= RING + TOY) continue;
        const int gr = oy + r;
        if (gr >= HW) continue;  // gr >= 0 guaranteed (oy >= -6, r >= 6)
        if (fullc) {
            float2* dst = reinterpret_cast<float2*>(&sout[img + (size_t)gr * HW + ox + c0]);
            f2 v0 = res[i][0], v1 = res[i][1];
            if (LAST) {
                v0 = (v0 + f2{1.0f, 1.0f}) * f2{0.5f, 0.5f};
                v1 = (v1 + f2{1.0f, 1.0f}) * f2{0.5f, 0.5f};
            }
            dst[0] = make_float2(v0.x, v0.y);
            dst[1] = make_float2(v1.x, v1.y);
        } else {
#pragma unroll
            for (int cl = 0; cl < 4; ++cl) {
                const int c = c0 + cl;
                if (c < RING || c >= RING + TOX) continue;
                const int gc = ox + c;
                if (gc < 0 || gc >= HW) continue;
                float v = res[i][cl >> 1][cl & 1];
                if (LAST) v = (v + 1.0f) * 0.5f;
                sout[img + (size_t)gr * HW + gc] = v;
            }
        }
    }
}

extern "C" void kernel_launch(void* const* d_in, const int* in_sizes, int n_in,
                              void* d_out, int out_size, void* d_ws, size_t ws_size,
                              hipStream_t stream) {
    const float* x = (const float*)d_in[0];
    const float* wA = (const float*)d_in[1];
    const float* wB = (const float*)d_in[2];
    const float* bias = (const float*)d_in[3];
    float* out = (float*)d_out;
    unsigned* mm = (unsigned*)d_ws;
    float* pong = (float*)((char*)d_ws + 1024);  // 128 MiB f32 buffer

    mm_init<<<1, 1, 0, stream>>>(mm);
    mm_reduce<<<2048, 256, 0, stream>>>((const float4*)x, mm, (int)(NELEM / 4));

    dim3 grid(NBX, NBY, NIMG);
    // steps 1-7: zeros -> out (scratch); 8-14: out -> pong; 15-21: pong -> out
    fused_k<1, 0><<<grid, 512, 0, stream>>>(x, nullptr, out, mm, wA, wB, bias);
    fused_k<0, 0><<<grid, 512, 0, stream>>>(x, out, pong, mm, wA, wB, bias);
    fused_k<0, 1><<<grid, 512, 0, stream>>>(x, pong, out, mm, wA, wB, bias);
}